// Round 5
// baseline (130.191 us; speedup 1.0000x reference)
//
#include <hip/hip_runtime.h>

// Problem constants (from reference)
#define NSTARS 2048
#define BATCH  256
#define PF     28
#define NGE    512
#define GF     32
#define OPD2   65536   // 256*256
#define KTOT   (PF + GF)  // 60
#define TM     16      // batches per block in main kernel
// main kernel: 256 threads * float4 = 1024 ij per block

typedef float v2f __attribute__((ext_vector_type(2)));
typedef float v4f __attribute__((ext_vector_type(4)));  // native vector: ok for nontemporal builtins

// ---------------------------------------------------------------------------
// Kernel 1: index search + W = [interm_poly | interm_graph] (k-major layout)
// Wt[k*BATCH + b], k in [0,60)
// ---------------------------------------------------------------------------
__global__ __launch_bounds__(256) void prep_kernel(
    const float* __restrict__ positions,  const float* __restrict__ obs_pos,
    const float* __restrict__ poly_dic,   const float* __restrict__ graph_dic,
    const float* __restrict__ alpha_poly, const float* __restrict__ alpha_graph,
    float* __restrict__ Wt)
{
    const int b = blockIdx.x;   // batch row
    const int t = threadIdx.x;  // 256 threads

    const float p0 = positions[2 * b];
    const float p1 = positions[2 * b + 1];

    // Faithful to argmax(eq.reshape(B,-1))//2 : first star n (row-major over
    // (n, coord)) where EITHER coordinate matches; all-false -> 0.
    int cand = 0x7fffffff;
    #pragma unroll
    for (int i = 0; i < NSTARS / 256; ++i) {
        const int n = t + i * 256;
        const float o0 = obs_pos[2 * n];
        const float o1 = obs_pos[2 * n + 1];
        if (o0 == p0 || o1 == p1) cand = min(cand, n);
    }
    __shared__ int smin[256];
    smin[t] = cand;
    __syncthreads();
    for (int s = 128; s > 0; s >>= 1) {
        if (t < s) smin[t] = min(smin[t], smin[t + s]);
        __syncthreads();
    }
    int idx = smin[0];
    if (idx == 0x7fffffff) idx = 0;  // argmax of all-False returns 0

    // interm_poly[j] = sum_p poly_dic[idx,p] * alpha_poly[p,j]
    if (t < PF) {
        float acc = 0.f;
        #pragma unroll
        for (int p = 0; p < PF; ++p)
            acc += poly_dic[idx * PF + p] * alpha_poly[p * PF + t];
        Wt[t * BATCH + b] = acc;
    }

    // interm_graph[g] = sum_e graph_dic[idx,e] * alpha_graph[e,g]
    // 8 partials of 64 elements each, reduced in LDS.
    __shared__ float psum[8][GF];
    {
        const int g = t & 31;
        const int r = t >> 5;
        float acc = 0.f;
        const int e0 = r * (NGE / 8);
        for (int e = e0; e < e0 + NGE / 8; ++e)
            acc += graph_dic[idx * NGE + e] * alpha_graph[e * GF + g];
        psum[r][g] = acc;
    }
    __syncthreads();
    if (t < GF) {
        float acc = 0.f;
        #pragma unroll
        for (int r = 0; r < 8; ++r) acc += psum[r][t];
        Wt[(PF + t) * BATCH + b] = acc;
    }
}

// ---------------------------------------------------------------------------
// Kernel 2: out[b, ij] = sum_k Wt[k, b] * S[k, ij]
// Tile: TM=16 batches x 1024 ij per block (256 thr x float4).
// grid (64,16) = 1024 blocks -> 4 blocks/CU; grid.x=64 multiple of 8 so
// same-ij-column blocks share an XCD (S slice 2 MB fits per-XCD L2).
// W tile in LDS (broadcast, conflict-free). unroll 4 -> 4 loads in flight.
// Non-temporal stores keep the 67 MB write stream out of L2.
// ---------------------------------------------------------------------------
__global__ __launch_bounds__(256, 4) void main_kernel(
    const float* __restrict__ S_poly, const float* __restrict__ S_graph,
    const float* __restrict__ Wt, float* __restrict__ out)
{
    __shared__ v4f wsh[KTOT][TM / 4];  // 60 x 4 float4 = 3.84 KB

    const int t  = threadIdx.x;
    const int ij = blockIdx.x * 1024 + t * 4;
    const int b0 = blockIdx.y * TM;

    // Stage Wt[k][b0..b0+15] into LDS
    for (int i = t; i < KTOT * (TM / 4); i += 256) {
        const int k = i / (TM / 4);
        const int q = i % (TM / 4);
        wsh[k][q] = *reinterpret_cast<const v4f*>(Wt + k * BATCH + b0 + q * 4);
    }
    __syncthreads();

    v2f acc[TM][2];
    #pragma unroll
    for (int b = 0; b < TM; ++b) { acc[b][0] = (v2f)0.f; acc[b][1] = (v2f)0.f; }

    const float* __restrict__ sp = S_poly  + ij;
    const float* __restrict__ sg = S_graph + ij;

    #pragma unroll 4
    for (int k = 0; k < PF; ++k) {
        const v4f s = *reinterpret_cast<const v4f*>(sp + (size_t)k * OPD2);
        v2f s01; s01.x = s.x; s01.y = s.y;
        v2f s23; s23.x = s.z; s23.y = s.w;
        #pragma unroll
        for (int q = 0; q < TM / 4; ++q) {
            const v4f w4 = wsh[k][q];
            acc[q * 4 + 0][0] += w4.x * s01;  acc[q * 4 + 0][1] += w4.x * s23;
            acc[q * 4 + 1][0] += w4.y * s01;  acc[q * 4 + 1][1] += w4.y * s23;
            acc[q * 4 + 2][0] += w4.z * s01;  acc[q * 4 + 2][1] += w4.z * s23;
            acc[q * 4 + 3][0] += w4.w * s01;  acc[q * 4 + 3][1] += w4.w * s23;
        }
    }
    #pragma unroll 4
    for (int k = 0; k < GF; ++k) {
        const v4f s = *reinterpret_cast<const v4f*>(sg + (size_t)k * OPD2);
        v2f s01; s01.x = s.x; s01.y = s.y;
        v2f s23; s23.x = s.z; s23.y = s.w;
        #pragma unroll
        for (int q = 0; q < TM / 4; ++q) {
            const v4f w4 = wsh[PF + k][q];
            acc[q * 4 + 0][0] += w4.x * s01;  acc[q * 4 + 0][1] += w4.x * s23;
            acc[q * 4 + 1][0] += w4.y * s01;  acc[q * 4 + 1][1] += w4.y * s23;
            acc[q * 4 + 2][0] += w4.z * s01;  acc[q * 4 + 2][1] += w4.z * s23;
            acc[q * 4 + 3][0] += w4.w * s01;  acc[q * 4 + 3][1] += w4.w * s23;
        }
    }

    #pragma unroll
    for (int b = 0; b < TM; ++b) {
        v4f r;
        r.x = acc[b][0].x; r.y = acc[b][0].y;
        r.z = acc[b][1].x; r.w = acc[b][1].y;
        __builtin_nontemporal_store(r,
            reinterpret_cast<v4f*>(out + (size_t)(b0 + b) * OPD2 + ij));
    }
}

// ---------------------------------------------------------------------------
extern "C" void kernel_launch(void* const* d_in, const int* in_sizes, int n_in,
                              void* d_out, int out_size, void* d_ws, size_t ws_size,
                              hipStream_t stream) {
    const float* positions   = (const float*)d_in[0];  // (256, 2)
    const float* obs_pos     = (const float*)d_in[1];  // (2048, 2)
    const float* poly_dic    = (const float*)d_in[2];  // (2048, 28)
    const float* graph_dic   = (const float*)d_in[3];  // (2048, 512)
    const float* alpha_poly  = (const float*)d_in[4];  // (28, 28)
    const float* alpha_graph = (const float*)d_in[5];  // (512, 32)
    const float* S_poly      = (const float*)d_in[6];  // (28, 256, 256)
    const float* S_graph     = (const float*)d_in[7];  // (32, 256, 256)
    float* out = (float*)d_out;                        // (256, 256, 256)

    float* Wt = (float*)d_ws;  // KTOT * BATCH floats = 240 KB

    prep_kernel<<<BATCH, 256, 0, stream>>>(positions, obs_pos, poly_dic,
                                           graph_dic, alpha_poly, alpha_graph,
                                           Wt);

    dim3 grid(OPD2 / 1024, BATCH / TM);  // 64 x 16 = 1024 blocks
    main_kernel<<<grid, 256, 0, stream>>>(S_poly, S_graph, Wt, out);
}

// Round 6
// 127.462 us; speedup vs baseline: 1.0214x; 1.0214x over previous
//
#include <hip/hip_runtime.h>

// Problem constants (from reference)
#define NSTARS 2048
#define BATCH  256
#define PF     28
#define NGE    512
#define GF     32
#define OPD2   65536   // 256*256
#define KTOT   (PF + GF)  // 60
#define TM     8       // batches per block in main kernel
// main kernel: 256 threads * float4 = 1024 ij per block

typedef float v2f __attribute__((ext_vector_type(2)));
typedef float v4f __attribute__((ext_vector_type(4)));  // native vector: ok for nontemporal builtins

// ---------------------------------------------------------------------------
// Kernel 1: index search + W = [interm_poly | interm_graph] (k-major layout)
// Wt[k*BATCH + b], k in [0,60)
// ---------------------------------------------------------------------------
__global__ __launch_bounds__(256) void prep_kernel(
    const float* __restrict__ positions,  const float* __restrict__ obs_pos,
    const float* __restrict__ poly_dic,   const float* __restrict__ graph_dic,
    const float* __restrict__ alpha_poly, const float* __restrict__ alpha_graph,
    float* __restrict__ Wt)
{
    const int b = blockIdx.x;   // batch row
    const int t = threadIdx.x;  // 256 threads

    const float p0 = positions[2 * b];
    const float p1 = positions[2 * b + 1];

    // Faithful to argmax(eq.reshape(B,-1))//2 : first star n (row-major over
    // (n, coord)) where EITHER coordinate matches; all-false -> 0.
    int cand = 0x7fffffff;
    #pragma unroll
    for (int i = 0; i < NSTARS / 256; ++i) {
        const int n = t + i * 256;
        const float o0 = obs_pos[2 * n];
        const float o1 = obs_pos[2 * n + 1];
        if (o0 == p0 || o1 == p1) cand = min(cand, n);
    }
    __shared__ int smin[256];
    smin[t] = cand;
    __syncthreads();
    for (int s = 128; s > 0; s >>= 1) {
        if (t < s) smin[t] = min(smin[t], smin[t + s]);
        __syncthreads();
    }
    int idx = smin[0];
    if (idx == 0x7fffffff) idx = 0;  // argmax of all-False returns 0

    // interm_poly[j] = sum_p poly_dic[idx,p] * alpha_poly[p,j]
    if (t < PF) {
        float acc = 0.f;
        #pragma unroll
        for (int p = 0; p < PF; ++p)
            acc += poly_dic[idx * PF + p] * alpha_poly[p * PF + t];
        Wt[t * BATCH + b] = acc;
    }

    // interm_graph[g] = sum_e graph_dic[idx,e] * alpha_graph[e,g]
    // 8 partials of 64 elements each, reduced in LDS.
    __shared__ float psum[8][GF];
    {
        const int g = t & 31;
        const int r = t >> 5;
        float acc = 0.f;
        const int e0 = r * (NGE / 8);
        for (int e = e0; e < e0 + NGE / 8; ++e)
            acc += graph_dic[idx * NGE + e] * alpha_graph[e * GF + g];
        psum[r][g] = acc;
    }
    __syncthreads();
    if (t < GF) {
        float acc = 0.f;
        #pragma unroll
        for (int r = 0; r < 8; ++r) acc += psum[r][t];
        Wt[(PF + t) * BATCH + b] = acc;
    }
}

// ---------------------------------------------------------------------------
// Kernel 2: out[b, ij] = sum_k Wt[k, b] * S[k, ij]
// Tile: TM=8 batches x 1024 ij per block (256 thr x float4).
// grid (64,32) = 2048 blocks -> 8 blocks/CU; acc = 32 VGPRs ->
// __launch_bounds__(256,6) targets ~6 waves/SIMD for latency hiding, and
// 8 staggered blocks/CU overlap store drains with compute.
// grid.x=64 multiple of 8: same-ij-column blocks share an XCD; per-XCD S
// column working set = 8 x 240 KB = 1.9 MB, fits 4 MB L2, so the 32x S
// re-read runs at L2 speed. Non-temporal stores keep the 67 MB output
// stream from evicting S.
// ---------------------------------------------------------------------------
__global__ __launch_bounds__(256, 6) void main_kernel(
    const float* __restrict__ S_poly, const float* __restrict__ S_graph,
    const float* __restrict__ Wt, float* __restrict__ out)
{
    __shared__ v4f wsh[KTOT][TM / 4];  // 60 x 2 v4f = 1.92 KB

    const int t  = threadIdx.x;
    const int ij = blockIdx.x * 1024 + t * 4;
    const int b0 = blockIdx.y * TM;

    // Stage Wt[k][b0..b0+7] into LDS (120 v4f loads)
    for (int i = t; i < KTOT * (TM / 4); i += 256) {
        const int k = i >> 1;
        const int q = i & 1;
        wsh[k][q] = *reinterpret_cast<const v4f*>(Wt + k * BATCH + b0 + q * 4);
    }
    __syncthreads();

    v2f acc[TM][2];
    #pragma unroll
    for (int b = 0; b < TM; ++b) { acc[b][0] = (v2f)0.f; acc[b][1] = (v2f)0.f; }

    const float* __restrict__ sp = S_poly  + ij;
    const float* __restrict__ sg = S_graph + ij;

    #pragma unroll 4
    for (int k = 0; k < PF; ++k) {
        const v4f s = *reinterpret_cast<const v4f*>(sp + (size_t)k * OPD2);
        v2f s01; s01.x = s.x; s01.y = s.y;
        v2f s23; s23.x = s.z; s23.y = s.w;
        #pragma unroll
        for (int q = 0; q < TM / 4; ++q) {
            const v4f w4 = wsh[k][q];
            acc[q * 4 + 0][0] += w4.x * s01;  acc[q * 4 + 0][1] += w4.x * s23;
            acc[q * 4 + 1][0] += w4.y * s01;  acc[q * 4 + 1][1] += w4.y * s23;
            acc[q * 4 + 2][0] += w4.z * s01;  acc[q * 4 + 2][1] += w4.z * s23;
            acc[q * 4 + 3][0] += w4.w * s01;  acc[q * 4 + 3][1] += w4.w * s23;
        }
    }
    #pragma unroll 4
    for (int k = 0; k < GF; ++k) {
        const v4f s = *reinterpret_cast<const v4f*>(sg + (size_t)k * OPD2);
        v2f s01; s01.x = s.x; s01.y = s.y;
        v2f s23; s23.x = s.z; s23.y = s.w;
        #pragma unroll
        for (int q = 0; q < TM / 4; ++q) {
            const v4f w4 = wsh[PF + k][q];
            acc[q * 4 + 0][0] += w4.x * s01;  acc[q * 4 + 0][1] += w4.x * s23;
            acc[q * 4 + 1][0] += w4.y * s01;  acc[q * 4 + 1][1] += w4.y * s23;
            acc[q * 4 + 2][0] += w4.z * s01;  acc[q * 4 + 2][1] += w4.z * s23;
            acc[q * 4 + 3][0] += w4.w * s01;  acc[q * 4 + 3][1] += w4.w * s23;
        }
    }

    #pragma unroll
    for (int b = 0; b < TM; ++b) {
        v4f r;
        r.x = acc[b][0].x; r.y = acc[b][0].y;
        r.z = acc[b][1].x; r.w = acc[b][1].y;
        __builtin_nontemporal_store(r,
            reinterpret_cast<v4f*>(out + (size_t)(b0 + b) * OPD2 + ij));
    }
}

// ---------------------------------------------------------------------------
extern "C" void kernel_launch(void* const* d_in, const int* in_sizes, int n_in,
                              void* d_out, int out_size, void* d_ws, size_t ws_size,
                              hipStream_t stream) {
    const float* positions   = (const float*)d_in[0];  // (256, 2)
    const float* obs_pos     = (const float*)d_in[1];  // (2048, 2)
    const float* poly_dic    = (const float*)d_in[2];  // (2048, 28)
    const float* graph_dic   = (const float*)d_in[3];  // (2048, 512)
    const float* alpha_poly  = (const float*)d_in[4];  // (28, 28)
    const float* alpha_graph = (const float*)d_in[5];  // (512, 32)
    const float* S_poly      = (const float*)d_in[6];  // (28, 256, 256)
    const float* S_graph     = (const float*)d_in[7];  // (32, 256, 256)
    float* out = (float*)d_out;                        // (256, 256, 256)

    float* Wt = (float*)d_ws;  // KTOT * BATCH floats = 240 KB

    prep_kernel<<<BATCH, 256, 0, stream>>>(positions, obs_pos, poly_dic,
                                           graph_dic, alpha_poly, alpha_graph,
                                           Wt);

    dim3 grid(OPD2 / 1024, BATCH / TM);  // 64 x 32 = 2048 blocks
    main_kernel<<<grid, 256, 0, stream>>>(S_poly, S_graph, Wt, out);
}